// Round 15
// baseline (105.947 us; speedup 1.0000x reference)
//
#include <hip/hip_runtime.h>
#include <hip/hip_bf16.h>

using u16 = unsigned short;
using u32 = unsigned int;
using u64 = unsigned long long;
typedef __attribute__((ext_vector_type(8))) short short8;
typedef __attribute__((ext_vector_type(4))) float f32x4;
typedef __attribute__((ext_vector_type(16))) float f32x16;
typedef __attribute__((ext_vector_type(4))) u32 u32x4;

constexpr int kB = 16, kNL = 512, kEL = 1024, kD = 256, kH = 8, kHD = 32;
constexpr int kS = kNL + kEL;      // 1536
constexpr int kM1 = kB * kNL;      // 8192
constexpr float kScale = 0.17677669529663687f;  // 1/sqrt(32)
constexpr float kLog2e = 1.4426950408889634f;
constexpr float kQS = kScale * kLog2e;          // folded into q at GEMM1 epilogue
constexpr float kEps = 1e-5f;

__device__ __forceinline__ u16 f2bh(float f) {
    __hip_bfloat16 h = __float2bfloat16(f);   // RNE
    return __builtin_bit_cast(u16, h);
}
__device__ __forceinline__ u32 packbf(float lo, float hi) {  // trunc pair (P >= 0)
    return (__float_as_uint(hi) & 0xffff0000u) | (__float_as_uint(lo) >> 16);
}
__device__ __forceinline__ void load4(const float* p, float* o) {
    float4 v = *reinterpret_cast<const float4*>(p);
    o[0] = v.x; o[1] = v.y; o[2] = v.z; o[3] = v.w;
}
__device__ __forceinline__ f32x16 fzero16() {
    f32x16 z;
    #pragma unroll
    for (int i = 0; i < 16; ++i) z[i] = 0.f;
    return z;
}

// ---------- mask bitmap: bit t of Mw[b*512+row] = any masked key in tile t ----------
__global__ __launch_bounds__(256) void mask_prep(
    const u32* __restrict__ mask, u32* __restrict__ Mw)
{
    const int row = blockIdx.x * 4 + (threadIdx.x >> 6);
    const int l = threadIdx.x & 63;
    const u32* mr = mask + (size_t)row * (kS / 4);
    u32 word = 0;
    #pragma unroll
    for (int k = 0; k < 6; ++k) {
        const u32 v = mr[k * 64 + l];
        const u64 bal = __ballot(v != 0);
        word |= (((bal) & 0xffffull) ? 1u : 0u) << (k * 4 + 0);
        word |= (((bal >> 16) & 0xffffull) ? 1u : 0u) << (k * 4 + 1);
        word |= (((bal >> 32) & 0xffffull) ? 1u : 0u) << (k * 4 + 2);
        word |= (((bal >> 48) & 0xffffull) ? 1u : 0u) << (k * 4 + 3);
    }
    if (l == 0) Mw[row] = word;
}

// ---------- prep: weight transpose/cast + node_x/edge_x bf16 cast ----------
__global__ __launch_bounds__(256) void prep_k(
    const float* __restrict__ W1, const float* __restrict__ W2,
    const float* __restrict__ l1w, const float* __restrict__ l2w,
    const float* __restrict__ nodef, const float* __restrict__ edgef,
    u16* __restrict__ Wt1, u16* __restrict__ Wt2,
    u16* __restrict__ Wt3, u16* __restrict__ Wt4,
    u16* __restrict__ nodeb, u16* __restrict__ edgeb)
{
    const int sec = blockIdx.y, bid = blockIdx.x, t = threadIdx.x;
    if (sec >= 4) {   // bulk bf16 casts
        const float* src = (sec == 4) ? nodef : edgef;
        u16* dst = (sec == 4) ? nodeb : edgeb;
        const int nblk = (sec == 4) ? 2048 : 4096;
        if (bid >= nblk) return;
        const int i = bid * 1024 + t * 4;
        float v[4]; load4(src + i, v);
        ushort4 o = {f2bh(v[0]), f2bh(v[1]), f2bh(v[2]), f2bh(v[3])};
        *reinterpret_cast<ushort4*>(dst + i) = o;
        return;
    }
    if (sec >= 2) {
        if (bid >= 64) return;
        const float* src = (sec == 2) ? l1w : l2w;
        u16* dst = (sec == 2) ? Wt3 : Wt4;
        const int i = bid * 1024 + t * 4;
        float v[4]; load4(src + i, v);
        ushort4 o = {f2bh(v[0]), f2bh(v[1]), f2bh(v[2]), f2bh(v[3])};
        *reinterpret_cast<ushort4*>(dst + i) = o;
        return;
    }
    const int N = (sec == 0) ? 768 : 512;
    if (bid >= 8 * (N / 32)) return;
    const float* src = (sec == 0) ? W1 : W2;
    u16* dst = (sec == 0) ? Wt1 : Wt2;
    const int tk = bid / (N / 32), tn = bid % (N / 32);
    __shared__ float T[32][33];
    {
        const int k = t >> 3, n4 = (t & 7) * 4;
        float v[4]; load4(src + (size_t)(tk * 32 + k) * N + tn * 32 + n4, v);
        T[n4+0][k] = v[0]; T[n4+1][k] = v[1]; T[n4+2][k] = v[2]; T[n4+3][k] = v[3];
    }
    __syncthreads();
    {
        const int n = t >> 3, k4 = (t & 7) * 4;
        ushort4 o = {f2bh(T[n][k4+0]), f2bh(T[n][k4+1]),
                     f2bh(T[n][k4+2]), f2bh(T[n][k4+3])};
        *reinterpret_cast<ushort4*>(dst + (size_t)(tn*32 + n) * 256 + tk*32 + k4) = o;
    }
}

// ---------- MFMA GEMM: C[M,N] = A[M,K] bf16 @ Wt[N,K] bf16 + bias ----------
template<int BM, int N, int K, int MODE>
__global__ __launch_bounds__(256) void gemm_mfma(
    const u16* __restrict__ A, const u16* __restrict__ Wt,
    const float* __restrict__ bias,
    void* __restrict__ o0v, void* __restrict__ o1v, void* __restrict__ o2v)
{
    constexpr int MI = BM / 32;            // M-fragments per wave
    __shared__ u16 AsB[2][BM * 40];
    __shared__ u16 BsB[2][64 * 40];
    const int t = threadIdx.x;
    const int w = t >> 6, l = t & 63;
    const int wr = w >> 1, wc = w & 1;
    const int lq = l & 15, lg = l >> 4;
    const int bm = blockIdx.x * BM, bn = blockIdx.y * 64;

    f32x4 acc[MI][2];
    #pragma unroll
    for (int mi = 0; mi < MI; ++mi)
        #pragma unroll
        for (int ni = 0; ni < 2; ++ni) acc[mi][ni] = (f32x4){0.f, 0.f, 0.f, 0.f};

    auto stage = [&](int buf, int kk) {
        u16* As = AsB[buf];
        u16* Bs = BsB[buf];
        if constexpr (BM == 128) {
            const int m = t >> 1, kh = (t & 1) * 16;
            const u16* ap = A + (size_t)(bm + m) * K + kk + kh;
            short8 x0 = *reinterpret_cast<const short8*>(ap);
            short8 x1 = *reinterpret_cast<const short8*>(ap + 8);
            *reinterpret_cast<short8*>(&As[m * 40 + kh]) = x0;
            *reinterpret_cast<short8*>(&As[m * 40 + kh + 8]) = x1;
        } else {
            const int m = t >> 2, kq = (t & 3) * 8;
            *reinterpret_cast<short8*>(&As[m * 40 + kq]) =
                *reinterpret_cast<const short8*>(A + (size_t)(bm + m) * K + kk + kq);
        }
        const int n = t >> 2, kq = (t & 3) * 8;
        *reinterpret_cast<short8*>(&Bs[n * 40 + kq]) =
            *reinterpret_cast<const short8*>(Wt + (size_t)(bn + n) * K + kk + kq);
    };

    stage(0, 0);
    __syncthreads();
    int buf = 0;
    for (int kk = 0; kk < K; kk += 32) {
        if (kk + 32 < K) stage(buf ^ 1, kk + 32);
        const u16* As = AsB[buf];
        const u16* Bs = BsB[buf];
        short8 bf[2];
        #pragma unroll
        for (int ni = 0; ni < 2; ++ni)
            bf[ni] = *reinterpret_cast<const short8*>(
                &Bs[(wc * 32 + ni * 16 + lq) * 40 + lg * 8]);
        #pragma unroll
        for (int mi = 0; mi < MI; ++mi) {
            const short8 af = *reinterpret_cast<const short8*>(
                &As[(wr * (MI * 16) + mi * 16 + lq) * 40 + lg * 8]);
            #pragma unroll
            for (int ni = 0; ni < 2; ++ni)
                acc[mi][ni] = __builtin_amdgcn_mfma_f32_16x16x32_bf16(
                    af, bf[ni], acc[mi][ni], 0, 0, 0);
        }
        __syncthreads();
        buf ^= 1;
    }

    #pragma unroll
    for (int mi = 0; mi < MI; ++mi) {
        #pragma unroll
        for (int ni = 0; ni < 2; ++ni) {
            const int cg = bn + wc * 32 + ni * 16 + lq;
            const int rg0 = bm + wr * (MI * 16) + mi * 16 + lg * 4;
            const float bv = bias[cg];
            float y[4];
            #pragma unroll
            for (int r = 0; r < 4; ++r) {
                y[r] = acc[mi][ni][r] + bv;
                if (MODE == 2) y[r] = fmaxf(y[r], 0.f);
            }
            if constexpr (MODE == 0) {
                u16* qo = (u16*)o0v; u16* ko = (u16*)o1v; u16* vt = (u16*)o2v;
                const int bidx = rg0 >> 9, key = rg0 & 511;
                if (cg < 256) {
                    #pragma unroll
                    for (int r = 0; r < 4; ++r)
                        qo[(size_t)(rg0 + r) * kD + cg] = f2bh(y[r] * kQS);
                } else if (cg < 512) {
                    #pragma unroll
                    for (int r = 0; r < 4; ++r)
                        ko[((size_t)bidx * kS + key + r) * kD + (cg - 256)] = f2bh(y[r]);
                } else {
                    const int d0 = cg - 512, hh = d0 >> 5, dd = d0 & 31;
                    ushort4 o = {f2bh(y[0]), f2bh(y[1]), f2bh(y[2]), f2bh(y[3])};
                    *reinterpret_cast<ushort4*>(
                        vt + ((size_t)(bidx * kH + hh) * kHD + dd) * kS + key) = o;
                }
            } else if constexpr (MODE == 1) {
                u16* ko = (u16*)o0v; u16* vt = (u16*)o1v;
                const int bidx = rg0 >> 10, key = kNL + (rg0 & 1023);
                if (cg < 256) {
                    #pragma unroll
                    for (int r = 0; r < 4; ++r)
                        ko[((size_t)bidx * kS + key + r) * kD + cg] = f2bh(y[r]);
                } else {
                    const int d0 = cg - 256, hh = d0 >> 5, dd = d0 & 31;
                    ushort4 o = {f2bh(y[0]), f2bh(y[1]), f2bh(y[2]), f2bh(y[3])};
                    *reinterpret_cast<ushort4*>(
                        vt + ((size_t)(bidx * kH + hh) * kHD + dd) * kS + key) = o;
                }
            } else if constexpr (MODE == 2) {   // relu -> bf16 hidden
                u16* o0 = (u16*)o0v;
                #pragma unroll
                for (int r = 0; r < 4; ++r)
                    o0[(size_t)(rg0 + r) * N + cg] = f2bh(y[r]);
            } else {
                float* o0 = (float*)o0v;
                #pragma unroll
                for (int r = 0; r < 4; ++r)
                    o0[(size_t)(rg0 + r) * N + cg] = y[r];
            }
        }
    }
}

// ---------- MFMA 32x32 flash attention, split-K x4, FOUR q-groups per wave ----------
// K/V fragment loads amortize over 128 q-rows: mem-ops per FLOP halved again
// (r14 proved this is the binding resource). 4 independent chains/tile = ILP.
__global__ __launch_bounds__(256) void attn_mfma(
    const u16* __restrict__ Qb, const u16* __restrict__ Kb,
    const u16* __restrict__ VTb, const unsigned char* __restrict__ mask,
    const u32* __restrict__ Mw, float* __restrict__ O)
{
    __shared__ float mba[4][64][17];
    __shared__ float mbb[4][64][17];
    const int t = threadIdx.x;
    const int w = t >> 6, l = t & 63;
    const int q32 = l & 31, hi = l >> 5;
    const int bid = blockIdx.x;
    const int h = bid & 7;
    const int qt = (bid >> 3) & 3;
    const int b = bid >> 5;
    const int qra = qt * 128 + q32;
    const int qrb = qra + 32, qrc = qra + 64, qrd = qra + 96;

    const u16* qpa = Qb + ((size_t)(b * kNL) + qra) * kD + h * kHD;
    const u16* qpb = Qb + ((size_t)(b * kNL) + qrb) * kD + h * kHD;
    const u16* qpc = Qb + ((size_t)(b * kNL) + qrc) * kD + h * kHD;
    const u16* qpd = Qb + ((size_t)(b * kNL) + qrd) * kD + h * kHD;
    const short8 qf0a = *reinterpret_cast<const short8*>(qpa + hi * 8);
    const short8 qf1a = *reinterpret_cast<const short8*>(qpa + 16 + hi * 8);
    const short8 qf0b = *reinterpret_cast<const short8*>(qpb + hi * 8);
    const short8 qf1b = *reinterpret_cast<const short8*>(qpb + 16 + hi * 8);
    const short8 qf0c = *reinterpret_cast<const short8*>(qpc + hi * 8);
    const short8 qf1c = *reinterpret_cast<const short8*>(qpc + 16 + hi * 8);
    const short8 qf0d = *reinterpret_cast<const short8*>(qpd + hi * 8);
    const short8 qf1d = *reinterpret_cast<const short8*>(qpd + 16 + hi * 8);

    const u16* kbase  = Kb  + ((size_t)b * kS) * kD + h * kHD;
    const u16* vtbase = VTb + ((size_t)(b * kH + h) * kHD) * kS;
    const unsigned char* mra = mask + ((size_t)(b * kNL) + qra) * kS;
    const unsigned char* mrb = mask + ((size_t)(b * kNL) + qrb) * kS;
    const unsigned char* mrc = mask + ((size_t)(b * kNL) + qrc) * kS;
    const unsigned char* mrd = mask + ((size_t)(b * kNL) + qrd) * kS;
    const u32 mbitsa = Mw[b * kNL + qra];
    const u32 mbitsb = Mw[b * kNL + qrb];
    const u32 mbitsc = Mw[b * kNL + qrc];
    const u32 mbitsd = Mw[b * kNL + qrd];

    f32x16 acca = fzero16(), accb = fzero16(), accc = fzero16(), accd = fzero16();
    float la = 0.f, lb = 0.f, lc = 0.f, ld = 0.f;

// one 32-key half for ONE q-group: QK (2 mfma) -> exp (bounded; -1e30 -> 0) -> PV (2 mfma)
#define HALFG(kfA, kfB, vfA, vfB, keyh, QF0, QF1, ACC, LRUN, COLD, MROW) do {  \
        f32x16 s = __builtin_amdgcn_mfma_f32_32x32x16_bf16(kfA, QF0, fzero16(), 0, 0, 0); \
        s = __builtin_amdgcn_mfma_f32_32x32x16_bf16(kfB, QF1, s, 0, 0, 0);     \
        float e[16];                                                           \
        _Pragma("unroll")                                                      \
        for (int n = 0; n < 16; ++n) e[n] = __builtin_amdgcn_exp2f(s[n]);      \
        if (COLD) {                                                            \
            _Pragma("unroll")                                                  \
            for (int n = 0; n < 16; ++n) {                                     \
                const int key = (keyh) + (n & 3) + 8 * (n >> 2) + 4 * hi;      \
                if (MROW[key]) e[n] = 0.f;                                     \
            }                                                                  \
        }                                                                      \
        u32 pk[8];                                                             \
        _Pragma("unroll")                                                      \
        for (int qd = 0; qd < 4; ++qd) {                                       \
            LRUN += (e[4*qd] + e[4*qd+1]) + (e[4*qd+2] + e[4*qd+3]);           \
            pk[2*qd]   = packbf(e[4*qd],   e[4*qd+1]);                         \
            pk[2*qd+1] = packbf(e[4*qd+2], e[4*qd+3]);                         \
        }                                                                      \
        {                                                                      \
            u32 xa = pk[0], ya = pk[2], xb = pk[1], yb = pk[3];                \
            asm("v_permlane32_swap_b32 %0, %1" : "+v"(xa), "+v"(ya));          \
            asm("v_permlane32_swap_b32 %0, %1" : "+v"(xb), "+v"(yb));          \
            const short8 pb = __builtin_bit_cast(short8, (u32x4){xa, xb, ya, yb}); \
            __builtin_amdgcn_s_setprio(1);                                     \
            ACC = __builtin_amdgcn_mfma_f32_32x32x16_bf16(vfA, pb, ACC, 0, 0, 0); \
            __builtin_amdgcn_s_setprio(0);                                     \
        }                                                                      \
        {                                                                      \
            u32 xa = pk[4], ya = pk[6], xb = pk[5], yb = pk[7];                \
            asm("v_permlane32_swap_b32 %0, %1" : "+v"(xa), "+v"(ya));          \
            asm("v_permlane32_swap_b32 %0, %1" : "+v"(xb), "+v"(yb));          \
            const short8 pb = __builtin_bit_cast(short8, (u32x4){xa, xb, ya, yb}); \
            __builtin_amdgcn_s_setprio(1);                                     \
            ACC = __builtin_amdgcn_mfma_f32_32x32x16_bf16(vfB, pb, ACC, 0, 0, 0); \
            __builtin_amdgcn_s_setprio(0);                                     \
        }                                                                      \
} while (0)

    const int ktBeg = w * 6, ktEnd = ktBeg + 6;
    for (int kt = ktBeg; kt < ktEnd; ++kt) {
        const int key0 = kt * 64;
        const u16* krow = kbase + (size_t)(key0 + q32) * kD + hi * 8;
        const u16* vrow = vtbase + (size_t)q32 * kS + key0 + hi * 8;
        const short8 a0 = *reinterpret_cast<const short8*>(krow);
        const short8 a1 = *reinterpret_cast<const short8*>(krow + 16);
        const short8 a2 = *reinterpret_cast<const short8*>(krow + 32 * kD);
        const short8 a3 = *reinterpret_cast<const short8*>(krow + 32 * kD + 16);
        const short8 v0 = *reinterpret_cast<const short8*>(vrow);
        const short8 v1 = *reinterpret_cast<const short8*>(vrow + 16);
        const short8 v2 = *reinterpret_cast<const short8*>(vrow + 32);
        const short8 v3 = *reinterpret_cast<const short8*>(vrow + 48);
        const bool ca = __any(((mbitsa >> kt) & 1u) != 0u);
        const bool cb = __any(((mbitsb >> kt) & 1u) != 0u);
        const bool cc = __any(((mbitsc >> kt) & 1u) != 0u);
        const bool cd = __any(((mbitsd >> kt) & 1u) != 0u);
        // half 0 (keys key0..+31): 4 q-groups share a0,a1,v0,v1
        HALFG(a0, a1, v0, v1, key0, qf0a, qf1a, acca, la, ca, mra);
        HALFG(a0, a1, v0, v1, key0, qf0b, qf1b, accb, lb, cb, mrb);
        HALFG(a0, a1, v0, v1, key0, qf0c, qf1c, accc, lc, cc, mrc);
        HALFG(a0, a1, v0, v1, key0, qf0d, qf1d, accd, ld, cd, mrd);
        // half 1 (keys key0+32..+63)
        HALFG(a2, a3, v2, v3, key0 + 32, qf0a, qf1a, acca, la, ca, mra);
        HALFG(a2, a3, v2, v3, key0 + 32, qf0b, qf1b, accb, lb, cb, mrb);
        HALFG(a2, a3, v2, v3, key0 + 32, qf0c, qf1c, accc, lc, cc, mrc);
        HALFG(a2, a3, v2, v3, key0 + 32, qf0d, qf1d, accd, ld, cd, mrd);
    }
#undef HALFG

    la += __shfl_xor(la, 32);
    lb += __shfl_xor(lb, 32);
    lc += __shfl_xor(lc, 32);
    ld += __shfl_xor(ld, 32);

// merge one q-group across the 4 split-K waves (w==0 only) and write O row
#define MERGE_OUT(MB, LRUN, ACC, QR) do {                                      \
        float lt = LRUN;                                                       \
        float ov[16];                                                          \
        _Pragma("unroll")                                                      \
        for (int i = 0; i < 16; ++i) ov[i] = ACC[i];                           \
        _Pragma("unroll")                                                      \
        for (int j = 1; j < 4; ++j) {                                          \
            lt += MB[j][l][0];                                                 \
            _Pragma("unroll")                                                  \
            for (int i = 0; i < 16; ++i) ov[i] += MB[j][l][1 + i];             \
        }                                                                      \
        const float inv = (lt > 0.f) ? 1.f / lt : 0.f;                         \
        float* orow = O + ((size_t)(b * kNL) + (QR)) * kD + h * kHD;           \
        _Pragma("unroll")                                                      \
        for (int qd = 0; qd < 4; ++qd) {                                       \
            float4 o = {ov[4*qd+0] * inv, ov[4*qd+1] * inv,                    \
                        ov[4*qd+2] * inv, ov[4*qd+3] * inv};                   \
            *reinterpret_cast<float4*>(orow + qd * 8 + 4 * hi) = o;            \
        }                                                                      \
} while (0)

    // stage 1: groups a, b
    mba[w][l][0] = la;
    mbb[w][l][0] = lb;
    #pragma unroll
    for (int j = 0; j < 16; ++j) { mba[w][l][1 + j] = acca[j]; mbb[w][l][1 + j] = accb[j]; }
    __syncthreads();
    if (w == 0) {
        MERGE_OUT(mba, la, acca, qra);
        MERGE_OUT(mbb, lb, accb, qrb);
    }
    __syncthreads();
    // stage 2: groups c, d (reuse buffers)
    mba[w][l][0] = lc;
    mbb[w][l][0] = ld;
    #pragma unroll
    for (int j = 0; j < 16; ++j) { mba[w][l][1 + j] = accc[j]; mbb[w][l][1 + j] = accd[j]; }
    __syncthreads();
    if (w == 0) {
        MERGE_OUT(mba, lc, accc, qrc);
        MERGE_OUT(mbb, ld, accd, qrd);
    }
#undef MERGE_OUT
}

// out = LayerNorm(a + r) * gamma + beta. DUAL: also write bf16 copy.
template<bool DUAL>
__global__ __launch_bounds__(256) void ln_k(
    const float* __restrict__ a_, const float* __restrict__ r,
    const float* __restrict__ gam, const float* __restrict__ bet,
    float* __restrict__ out_, u16* __restrict__ outh)
{
    const int row = blockIdx.x * 4 + (threadIdx.x >> 6);
    const int lane = threadIdx.x & 63;
    const size_t base = (size_t)row * kD + lane * 4;
    float xv[4];
    load4(a_ + base, xv);
    float rv[4];
    load4(r + base, rv);
    #pragma unroll
    for (int t = 0; t < 4; ++t) xv[t] += rv[t];
    float s = xv[0] + xv[1] + xv[2] + xv[3];
    float q = xv[0]*xv[0] + xv[1]*xv[1] + xv[2]*xv[2] + xv[3]*xv[3];
    #pragma unroll
    for (int off = 1; off < 64; off <<= 1) {
        s += __shfl_xor(s, off);
        q += __shfl_xor(q, off);
    }
    const float mean = s * (1.0f / kD);
    const float var = q * (1.0f / kD) - mean * mean;
    const float rs = rsqrtf(var + kEps);
    float gv[4], bv[4];
    load4(gam + lane * 4, gv);
    load4(bet + lane * 4, bv);
    float y[4];
    #pragma unroll
    for (int t = 0; t < 4; ++t) y[t] = (xv[t] - mean) * rs * gv[t] + bv[t];
    float4 o = {y[0], y[1], y[2], y[3]};
    *reinterpret_cast<float4*>(out_ + base) = o;
    if constexpr (DUAL) {
        ushort4 ob = {f2bh(y[0]), f2bh(y[1]), f2bh(y[2]), f2bh(y[3])};
        *reinterpret_cast<ushort4*>(outh + base) = ob;
    }
}

extern "C" void kernel_launch(void* const* d_in, const int* in_sizes, int n_in,
                              void* d_out, int out_size, void* d_ws, size_t ws_size,
                              hipStream_t stream)
{
    const float* node_x = (const float*)d_in[0];
    const float* edge_x = (const float*)d_in[1];
    const unsigned char* mask = (const unsigned char*)d_in[2];
    const float* W1  = (const float*)d_in[3];
    const float* b1  = (const float*)d_in[4];
    const float* W2  = (const float*)d_in[5];
    const float* b2  = (const float*)d_in[6];
    const float* l1w = (const float*)d_in[7];
    const float* l1b = (const float*)d_in[8];
    const float* l2w = (const float*)d_in[9];
    const float* l2b = (const float*)d_in[10];
    const float* g1  = (const float*)d_in[11];
    const float* be1 = (const float*)d_in[12];
    const float* g2  = (const float*)d_in[13];
    const float* be2 = (const float*)d_in[14];

    char* w = (char*)d_ws;
    u16*   qb  = (u16*)(w);                      // q bf16 4 MB   [0,4); later fh bf16
    u16*   wt1 = (u16*)(w + (4u<<20));           // 768x256 bf16
    u16*   wt2 = (u16*)(w + (4u<<20) + 393216);
    u16*   wt3 = (u16*)(w + (4u<<20) + 655360);
    u16*   wt4 = (u16*)(w + (4u<<20) + 786432);
    u32*   mw  = (u32*)(w + (4u<<20) + 917504);  // mask bitmap 32 KB
    u16*   nxb = (u16*)(w + (5u<<20));           // node bf16 4 MB  [5,9)
    u16*   exb = (u16*)(w + (9u<<20));           // edge bf16 8 MB  [9,17); later xbh
    u16*   kb  = (u16*)(w + (17u<<20));          // K bf16 12 MB    [17,30)
    u16*   vt  = (u16*)(w + (30u<<20));          // V^T bf16 12 MB  [30,43)
    float* cx  = (float*)(w + (43u<<20));        // ctx / ff out f32 8 MB [43,52)
    float* xb  = (float*)(w + (52u<<20));        // x after LN1 f32  8 MB [52,61)
    u16*   xbh = exb;                            // LN1 bf16 out (edge_bf dead)
    u16*   fh  = qb;                             // ffn hidden bf16 (qb dead)

    mask_prep<<<kM1 / 4, 256, 0, stream>>>((const u32*)mask, mw);
    prep_k<<<dim3(4096, 6), 256, 0, stream>>>(
        W1, W2, l1w, l2w, node_x, edge_x, wt1, wt2, wt3, wt4, nxb, exb);
    gemm_mfma<128, 768, 256, 0><<<dim3(kM1 / 128, 12), 256, 0, stream>>>(
        nxb, wt1, b1, qb, kb, vt);
    gemm_mfma<128, 512, 256, 1><<<dim3(kB * kEL / 128, 8), 256, 0, stream>>>(
        exb, wt2, b2, kb, vt, nullptr);
    attn_mfma<<<kB * kH * 4, 256, 0, stream>>>(qb, kb, vt, mask, mw, cx);
    ln_k<true><<<kM1 / 4, 256, 0, stream>>>(node_x, cx, g1, be1, xb, xbh);
    gemm_mfma<64, 256, 256, 2><<<dim3(kM1 / 64, 4), 256, 0, stream>>>(
        xbh, wt3, l1b, fh, nullptr, nullptr);
    gemm_mfma<64, 256, 256, 3><<<dim3(kM1 / 64, 4), 256, 0, stream>>>(
        fh, wt4, l2b, cx, nullptr, nullptr);
    ln_k<false><<<kM1 / 4, 256, 0, stream>>>(xb, cx, g2, be2, (float*)d_out, nullptr);
}

// Round 16
// 99.624 us; speedup vs baseline: 1.0635x; 1.0635x over previous
//
#include <hip/hip_runtime.h>
#include <hip/hip_bf16.h>

using u16 = unsigned short;
using u32 = unsigned int;
using u64 = unsigned long long;
typedef __attribute__((ext_vector_type(8))) short short8;
typedef __attribute__((ext_vector_type(4))) float f32x4;
typedef __attribute__((ext_vector_type(16))) float f32x16;
typedef __attribute__((ext_vector_type(4))) u32 u32x4;

constexpr int kB = 16, kNL = 512, kEL = 1024, kD = 256, kH = 8, kHD = 32;
constexpr int kS = kNL + kEL;      // 1536
constexpr int kM1 = kB * kNL;      // 8192
constexpr float kScale = 0.17677669529663687f;  // 1/sqrt(32)
constexpr float kLog2e = 1.4426950408889634f;
constexpr float kQS = kScale * kLog2e;          // folded into q at GEMM1 epilogue
constexpr float kEps = 1e-5f;

__device__ __forceinline__ u16 f2bh(float f) {
    __hip_bfloat16 h = __float2bfloat16(f);   // RNE
    return __builtin_bit_cast(u16, h);
}
__device__ __forceinline__ u32 packbf(float lo, float hi) {  // trunc pair (P >= 0)
    return (__float_as_uint(hi) & 0xffff0000u) | (__float_as_uint(lo) >> 16);
}
__device__ __forceinline__ void load4(const float* p, float* o) {
    float4 v = *reinterpret_cast<const float4*>(p);
    o[0] = v.x; o[1] = v.y; o[2] = v.z; o[3] = v.w;
}
__device__ __forceinline__ f32x16 fzero16() {
    f32x16 z;
    #pragma unroll
    for (int i = 0; i < 16; ++i) z[i] = 0.f;
    return z;
}

// ---------- prep: weight transpose/cast + input bf16 casts + mask bitmap ----------
__global__ __launch_bounds__(256) void prep_k(
    const float* __restrict__ W1, const float* __restrict__ W2,
    const float* __restrict__ l1w, const float* __restrict__ l2w,
    const float* __restrict__ nodef, const float* __restrict__ edgef,
    const u32* __restrict__ mask,
    u16* __restrict__ Wt1, u16* __restrict__ Wt2,
    u16* __restrict__ Wt3, u16* __restrict__ Wt4,
    u16* __restrict__ nodeb, u16* __restrict__ edgeb,
    u32* __restrict__ Mw)
{
    const int sec = blockIdx.y, bid = blockIdx.x, t = threadIdx.x;
    if (sec == 6) {   // mask bitmap: one wave per row-quad block
        if (bid >= 2048) return;
        const int row = bid * 4 + (t >> 6);
        const int l = t & 63;
        const u32* mr = mask + (size_t)row * (kS / 4);
        u32 word = 0;
        #pragma unroll
        for (int k = 0; k < 6; ++k) {
            const u32 v = mr[k * 64 + l];
            const u64 bal = __ballot(v != 0);
            word |= (((bal) & 0xffffull) ? 1u : 0u) << (k * 4 + 0);
            word |= (((bal >> 16) & 0xffffull) ? 1u : 0u) << (k * 4 + 1);
            word |= (((bal >> 32) & 0xffffull) ? 1u : 0u) << (k * 4 + 2);
            word |= (((bal >> 48) & 0xffffull) ? 1u : 0u) << (k * 4 + 3);
        }
        if (l == 0) Mw[row] = word;
        return;
    }
    if (sec >= 4) {   // bulk bf16 casts
        const float* src = (sec == 4) ? nodef : edgef;
        u16* dst = (sec == 4) ? nodeb : edgeb;
        const int nblk = (sec == 4) ? 2048 : 4096;
        if (bid >= nblk) return;
        const int i = bid * 1024 + t * 4;
        float v[4]; load4(src + i, v);
        ushort4 o = {f2bh(v[0]), f2bh(v[1]), f2bh(v[2]), f2bh(v[3])};
        *reinterpret_cast<ushort4*>(dst + i) = o;
        return;
    }
    if (sec >= 2) {
        if (bid >= 64) return;
        const float* src = (sec == 2) ? l1w : l2w;
        u16* dst = (sec == 2) ? Wt3 : Wt4;
        const int i = bid * 1024 + t * 4;
        float v[4]; load4(src + i, v);
        ushort4 o = {f2bh(v[0]), f2bh(v[1]), f2bh(v[2]), f2bh(v[3])};
        *reinterpret_cast<ushort4*>(dst + i) = o;
        return;
    }
    const int N = (sec == 0) ? 768 : 512;
    if (bid >= 8 * (N / 32)) return;
    const float* src = (sec == 0) ? W1 : W2;
    u16* dst = (sec == 0) ? Wt1 : Wt2;
    const int tk = bid / (N / 32), tn = bid % (N / 32);
    __shared__ float T[32][33];
    {
        const int k = t >> 3, n4 = (t & 7) * 4;
        float v[4]; load4(src + (size_t)(tk * 32 + k) * N + tn * 32 + n4, v);
        T[n4+0][k] = v[0]; T[n4+1][k] = v[1]; T[n4+2][k] = v[2]; T[n4+3][k] = v[3];
    }
    __syncthreads();
    {
        const int n = t >> 3, k4 = (t & 7) * 4;
        ushort4 o = {f2bh(T[n][k4+0]), f2bh(T[n][k4+1]),
                     f2bh(T[n][k4+2]), f2bh(T[n][k4+3])};
        *reinterpret_cast<ushort4*>(dst + (size_t)(tn*32 + n) * 256 + tk*32 + k4) = o;
    }
}

// ---------- MFMA GEMM: C[M,N] = A[M,K] bf16 @ Wt[N,K] bf16 + bias ----------
// 4 waves 2x2; each wave (BM/2)x(BN/2) output. 128x128: 16 mfma/K-step.
template<int BM, int BN, int N, int K, int MODE>
__global__ __launch_bounds__(256) void gemm_mfma(
    const u16* __restrict__ A, const u16* __restrict__ Wt,
    const float* __restrict__ bias,
    void* __restrict__ o0v, void* __restrict__ o1v, void* __restrict__ o2v)
{
    constexpr int MI = (BM / 2) / 16;      // M-fragments per wave
    constexpr int NI = (BN / 2) / 16;      // N-fragments per wave
    __shared__ u16 AsB[2][BM * 40];
    __shared__ u16 BsB[2][BN * 40];
    const int t = threadIdx.x;
    const int w = t >> 6, l = t & 63;
    const int wr = w >> 1, wc = w & 1;
    const int lq = l & 15, lg = l >> 4;
    const int bm = blockIdx.x * BM, bn = blockIdx.y * BN;

    f32x4 acc[MI][NI];
    #pragma unroll
    for (int mi = 0; mi < MI; ++mi)
        #pragma unroll
        for (int ni = 0; ni < NI; ++ni) acc[mi][ni] = (f32x4){0.f, 0.f, 0.f, 0.f};

    auto stage = [&](int buf, int kk) {
        u16* As = AsB[buf];
        u16* Bs = BsB[buf];
        if constexpr (BM == 128) {
            const int m = t >> 1, kh = (t & 1) * 16;
            const u16* ap = A + (size_t)(bm + m) * K + kk + kh;
            *reinterpret_cast<short8*>(&As[m * 40 + kh]) =
                *reinterpret_cast<const short8*>(ap);
            *reinterpret_cast<short8*>(&As[m * 40 + kh + 8]) =
                *reinterpret_cast<const short8*>(ap + 8);
        } else {
            const int m = t >> 2, kq = (t & 3) * 8;
            *reinterpret_cast<short8*>(&As[m * 40 + kq]) =
                *reinterpret_cast<const short8*>(A + (size_t)(bm + m) * K + kk + kq);
        }
        if constexpr (BN == 128) {
            const int n = t >> 1, kh = (t & 1) * 16;
            const u16* bp = Wt + (size_t)(bn + n) * K + kk + kh;
            *reinterpret_cast<short8*>(&Bs[n * 40 + kh]) =
                *reinterpret_cast<const short8*>(bp);
            *reinterpret_cast<short8*>(&Bs[n * 40 + kh + 8]) =
                *reinterpret_cast<const short8*>(bp + 8);
        } else {
            const int n = t >> 2, kq = (t & 3) * 8;
            *reinterpret_cast<short8*>(&Bs[n * 40 + kq]) =
                *reinterpret_cast<const short8*>(Wt + (size_t)(bn + n) * K + kk + kq);
        }
    };

    stage(0, 0);
    __syncthreads();
    int buf = 0;
    for (int kk = 0; kk < K; kk += 32) {
        if (kk + 32 < K) stage(buf ^ 1, kk + 32);
        const u16* As = AsB[buf];
        const u16* Bs = BsB[buf];
        short8 bf[NI];
        #pragma unroll
        for (int ni = 0; ni < NI; ++ni)
            bf[ni] = *reinterpret_cast<const short8*>(
                &Bs[(wc * (BN / 2) + ni * 16 + lq) * 40 + lg * 8]);
        #pragma unroll
        for (int mi = 0; mi < MI; ++mi) {
            const short8 af = *reinterpret_cast<const short8*>(
                &As[(wr * (BM / 2) + mi * 16 + lq) * 40 + lg * 8]);
            #pragma unroll
            for (int ni = 0; ni < NI; ++ni)
                acc[mi][ni] = __builtin_amdgcn_mfma_f32_16x16x32_bf16(
                    af, bf[ni], acc[mi][ni], 0, 0, 0);
        }
        __syncthreads();
        buf ^= 1;
    }

    #pragma unroll
    for (int mi = 0; mi < MI; ++mi) {
        #pragma unroll
        for (int ni = 0; ni < NI; ++ni) {
            const int cg = bn + wc * (BN / 2) + ni * 16 + lq;
            const int rg0 = bm + wr * (BM / 2) + mi * 16 + lg * 4;
            const float bv = bias[cg];
            float y[4];
            #pragma unroll
            for (int r = 0; r < 4; ++r) {
                y[r] = acc[mi][ni][r] + bv;
                if (MODE == 2) y[r] = fmaxf(y[r], 0.f);
            }
            if constexpr (MODE == 0) {
                u16* qo = (u16*)o0v; u16* ko = (u16*)o1v; u16* vt = (u16*)o2v;
                const int bidx = rg0 >> 9, key = rg0 & 511;
                if (cg < 256) {
                    #pragma unroll
                    for (int r = 0; r < 4; ++r)
                        qo[(size_t)(rg0 + r) * kD + cg] = f2bh(y[r] * kQS);
                } else if (cg < 512) {
                    #pragma unroll
                    for (int r = 0; r < 4; ++r)
                        ko[((size_t)bidx * kS + key + r) * kD + (cg - 256)] = f2bh(y[r]);
                } else {
                    const int d0 = cg - 512, hh = d0 >> 5, dd = d0 & 31;
                    ushort4 o = {f2bh(y[0]), f2bh(y[1]), f2bh(y[2]), f2bh(y[3])};
                    *reinterpret_cast<ushort4*>(
                        vt + ((size_t)(bidx * kH + hh) * kHD + dd) * kS + key) = o;
                }
            } else if constexpr (MODE == 1) {
                u16* ko = (u16*)o0v; u16* vt = (u16*)o1v;
                const int bidx = rg0 >> 10, key = kNL + (rg0 & 1023);
                if (cg < 256) {
                    #pragma unroll
                    for (int r = 0; r < 4; ++r)
                        ko[((size_t)bidx * kS + key + r) * kD + cg] = f2bh(y[r]);
                } else {
                    const int d0 = cg - 256, hh = d0 >> 5, dd = d0 & 31;
                    ushort4 o = {f2bh(y[0]), f2bh(y[1]), f2bh(y[2]), f2bh(y[3])};
                    *reinterpret_cast<ushort4*>(
                        vt + ((size_t)(bidx * kH + hh) * kHD + dd) * kS + key) = o;
                }
            } else if constexpr (MODE == 2) {   // relu -> bf16 hidden
                u16* o0 = (u16*)o0v;
                #pragma unroll
                for (int r = 0; r < 4; ++r)
                    o0[(size_t)(rg0 + r) * N + cg] = f2bh(y[r]);
            } else {
                float* o0 = (float*)o0v;
                #pragma unroll
                for (int r = 0; r < 4; ++r)
                    o0[(size_t)(rg0 + r) * N + cg] = y[r];
            }
        }
    }
}

// ---------- MFMA 32x32 flash attention, split-K x4, 2 q-groups per wave (r14) ----------
__global__ __launch_bounds__(256) void attn_mfma(
    const u16* __restrict__ Qb, const u16* __restrict__ Kb,
    const u16* __restrict__ VTb, const unsigned char* __restrict__ mask,
    const u32* __restrict__ Mw, float* __restrict__ O)
{
    __shared__ float mba[4][64][17];
    __shared__ float mbb[4][64][17];
    const int t = threadIdx.x;
    const int w = t >> 6, l = t & 63;
    const int q32 = l & 31, hi = l >> 5;
    const int bid = blockIdx.x;
    const int h = bid & 7;
    const int qt = (bid >> 3) & 7;
    const int b = bid >> 6;
    const int qra = qt * 64 + q32;
    const int qrb = qra + 32;

    const u16* qpa = Qb + ((size_t)(b * kNL) + qra) * kD + h * kHD;
    const u16* qpb = Qb + ((size_t)(b * kNL) + qrb) * kD + h * kHD;
    const short8 qf0a = *reinterpret_cast<const short8*>(qpa + hi * 8);
    const short8 qf1a = *reinterpret_cast<const short8*>(qpa + 16 + hi * 8);
    const short8 qf0b = *reinterpret_cast<const short8*>(qpb + hi * 8);
    const short8 qf1b = *reinterpret_cast<const short8*>(qpb + 16 + hi * 8);

    const u16* kbase  = Kb  + ((size_t)b * kS) * kD + h * kHD;
    const u16* vtbase = VTb + ((size_t)(b * kH + h) * kHD) * kS;
    const unsigned char* mra = mask + ((size_t)(b * kNL) + qra) * kS;
    const unsigned char* mrb = mask + ((size_t)(b * kNL) + qrb) * kS;
    const u32 mbitsa = Mw[b * kNL + qra];
    const u32 mbitsb = Mw[b * kNL + qrb];

    f32x16 acca = fzero16(), accb = fzero16();
    float la = 0.f, lb = 0.f;

#define HALFG(kfA, kfB, vfA, vfB, keyh, QF0, QF1, ACC, LRUN, COLD, MROW) do {  \
        f32x16 s = __builtin_amdgcn_mfma_f32_32x32x16_bf16(kfA, QF0, fzero16(), 0, 0, 0); \
        s = __builtin_amdgcn_mfma_f32_32x32x16_bf16(kfB, QF1, s, 0, 0, 0);     \
        float e[16];                                                           \
        _Pragma("unroll")                                                      \
        for (int n = 0; n < 16; ++n) e[n] = __builtin_amdgcn_exp2f(s[n]);      \
        if (COLD) {                                                            \
            _Pragma("unroll")                                                  \
            for (int n = 0; n < 16; ++n) {                                     \
                const int key = (keyh) + (n & 3) + 8 * (n >> 2) + 4 * hi;      \
                if (MROW[key]) e[n] = 0.f;                                     \
            }                                                                  \
        }                                                                      \
        u32 pk[8];                                                             \
        _Pragma("unroll")                                                      \
        for (int qd = 0; qd < 4; ++qd) {                                       \
            LRUN += (e[4*qd] + e[4*qd+1]) + (e[4*qd+2] + e[4*qd+3]);           \
            pk[2*qd]   = packbf(e[4*qd],   e[4*qd+1]);                         \
            pk[2*qd+1] = packbf(e[4*qd+2], e[4*qd+3]);                         \
        }                                                                      \
        {                                                                      \
            u32 xa = pk[0], ya = pk[2], xb = pk[1], yb = pk[3];                \
            asm("v_permlane32_swap_b32 %0, %1" : "+v"(xa), "+v"(ya));          \
            asm("v_permlane32_swap_b32 %0, %1" : "+v"(xb), "+v"(yb));          \
            const short8 pb = __builtin_bit_cast(short8, (u32x4){xa, xb, ya, yb}); \
            __builtin_amdgcn_s_setprio(1);                                     \
            ACC = __builtin_amdgcn_mfma_f32_32x32x16_bf16(vfA, pb, ACC, 0, 0, 0); \
            __builtin_amdgcn_s_setprio(0);                                     \
        }                                                                      \
        {                                                                      \
            u32 xa = pk[4], ya = pk[6], xb = pk[5], yb = pk[7];                \
            asm("v_permlane32_swap_b32 %0, %1" : "+v"(xa), "+v"(ya));          \
            asm("v_permlane32_swap_b32 %0, %1" : "+v"(xb), "+v"(yb));          \
            const short8 pb = __builtin_bit_cast(short8, (u32x4){xa, xb, ya, yb}); \
            __builtin_amdgcn_s_setprio(1);                                     \
            ACC = __builtin_amdgcn_mfma_f32_32x32x16_bf16(vfB, pb, ACC, 0, 0, 0); \
            __builtin_amdgcn_s_setprio(0);                                     \
        }                                                                      \
} while (0)

    const int ktBeg = w * 6, ktEnd = ktBeg + 6;
    for (int kt = ktBeg; kt < ktEnd; ++kt) {
        const int key0 = kt * 64;
        const u16* krow = kbase + (size_t)(key0 + q32) * kD + hi * 8;
        const u16* vrow = vtbase + (size_t)q32 * kS + key0 + hi * 8;
        const short8 a0 = *reinterpret_cast<const short8*>(krow);
        const short8 a1 = *reinterpret_cast<const short8*>(krow + 16);
        const short8 a2 = *reinterpret_cast<const short8*>(krow + 32 * kD);
        const short8 a3 = *reinterpret_cast<const short8*>(krow + 32 * kD + 16);
        const short8 v0 = *reinterpret_cast<const short8*>(vrow);
        const short8 v1 = *reinterpret_cast<const short8*>(vrow + 16);
        const short8 v2 = *reinterpret_cast<const short8*>(vrow + 32);
        const short8 v3 = *reinterpret_cast<const short8*>(vrow + 48);
        const bool colda = __any(((mbitsa >> kt) & 1u) != 0u);
        const bool coldb = __any(((mbitsb >> kt) & 1u) != 0u);
        HALFG(a0, a1, v0, v1, key0, qf0a, qf1a, acca, la, colda, mra);
        HALFG(a0, a1, v0, v1, key0, qf0b, qf1b, accb, lb, coldb, mrb);
        HALFG(a2, a3, v2, v3, key0 + 32, qf0a, qf1a, acca, la, colda, mra);
        HALFG(a2, a3, v2, v3, key0 + 32, qf0b, qf1b, accb, lb, coldb, mrb);
    }
#undef HALFG

    la += __shfl_xor(la, 32);
    lb += __shfl_xor(lb, 32);

    mba[w][l][0] = la;
    mbb[w][l][0] = lb;
    #pragma unroll
    for (int j = 0; j < 16; ++j) { mba[w][l][1 + j] = acca[j]; mbb[w][l][1 + j] = accb[j]; }
    __syncthreads();
    if (w == 0) {
        {   // group a
            float lt = la;
            float ov[16];
            #pragma unroll
            for (int i = 0; i < 16; ++i) ov[i] = acca[i];
            #pragma unroll
            for (int j = 1; j < 4; ++j) {
                lt += mba[j][l][0];
                #pragma unroll
                for (int i = 0; i < 16; ++i) ov[i] += mba[j][l][1 + i];
            }
            const float inv = (lt > 0.f) ? 1.f / lt : 0.f;
            float* orow = O + ((size_t)(b * kNL) + qra) * kD + h * kHD;
            #pragma unroll
            for (int qd = 0; qd < 4; ++qd) {
                float4 o = {ov[4*qd+0] * inv, ov[4*qd+1] * inv,
                            ov[4*qd+2] * inv, ov[4*qd+3] * inv};
                *reinterpret_cast<float4*>(orow + qd * 8 + 4 * hi) = o;
            }
        }
        {   // group b
            float lt = lb;
            float ov[16];
            #pragma unroll
            for (int i = 0; i < 16; ++i) ov[i] = accb[i];
            #pragma unroll
            for (int j = 1; j < 4; ++j) {
                lt += mbb[j][l][0];
                #pragma unroll
                for (int i = 0; i < 16; ++i) ov[i] += mbb[j][l][1 + i];
            }
            const float inv = (lt > 0.f) ? 1.f / lt : 0.f;
            float* orow = O + ((size_t)(b * kNL) + qrb) * kD + h * kHD;
            #pragma unroll
            for (int qd = 0; qd < 4; ++qd) {
                float4 o = {ov[4*qd+0] * inv, ov[4*qd+1] * inv,
                            ov[4*qd+2] * inv, ov[4*qd+3] * inv};
                *reinterpret_cast<float4*>(orow + qd * 8 + 4 * hi) = o;
            }
        }
    }
}

// out = LayerNorm(a + r) * gamma + beta. DUAL: also write bf16 copy.
template<bool DUAL>
__global__ __launch_bounds__(256) void ln_k(
    const float* __restrict__ a_, const float* __restrict__ r,
    const float* __restrict__ gam, const float* __restrict__ bet,
    float* __restrict__ out_, u16* __restrict__ outh)
{
    const int row = blockIdx.x * 4 + (threadIdx.x >> 6);
    const int lane = threadIdx.x & 63;
    const size_t base = (size_t)row * kD + lane * 4;
    float xv[4];
    load4(a_ + base, xv);
    float rv[4];
    load4(r + base, rv);
    #pragma unroll
    for (int t = 0; t < 4; ++t) xv[t] += rv[t];
    float s = xv[0] + xv[1] + xv[2] + xv[3];
    float q = xv[0]*xv[0] + xv[1]*xv[1] + xv[2]*xv[2] + xv[3]*xv[3];
    #pragma unroll
    for (int off = 1; off < 64; off <<= 1) {
        s += __shfl_xor(s, off);
        q += __shfl_xor(q, off);
    }
    const float mean = s * (1.0f / kD);
    const float var = q * (1.0f / kD) - mean * mean;
    const float rs = rsqrtf(var + kEps);
    float gv[4], bv[4];
    load4(gam + lane * 4, gv);
    load4(bet + lane * 4, bv);
    float y[4];
    #pragma unroll
    for (int t = 0; t < 4; ++t) y[t] = (xv[t] - mean) * rs * gv[t] + bv[t];
    float4 o = {y[0], y[1], y[2], y[3]};
    *reinterpret_cast<float4*>(out_ + base) = o;
    if constexpr (DUAL) {
        ushort4 ob = {f2bh(y[0]), f2bh(y[1]), f2bh(y[2]), f2bh(y[3])};
        *reinterpret_cast<ushort4*>(outh + base) = ob;
    }
}

extern "C" void kernel_launch(void* const* d_in, const int* in_sizes, int n_in,
                              void* d_out, int out_size, void* d_ws, size_t ws_size,
                              hipStream_t stream)
{
    const float* node_x = (const float*)d_in[0];
    const float* edge_x = (const float*)d_in[1];
    const unsigned char* mask = (const unsigned char*)d_in[2];
    const float* W1  = (const float*)d_in[3];
    const float* b1  = (const float*)d_in[4];
    const float* W2  = (const float*)d_in[5];
    const float* b2  = (const float*)d_in[6];
    const float* l1w = (const float*)d_in[7];
    const float* l1b = (const float*)d_in[8];
    const float* l2w = (const float*)d_in[9];
    const float* l2b = (const float*)d_in[10];
    const float* g1  = (const float*)d_in[11];
    const float* be1 = (const float*)d_in[12];
    const float* g2  = (const float*)d_in[13];
    const float* be2 = (const float*)d_in[14];

    char* w = (char*)d_ws;
    u16*   qb  = (u16*)(w);                      // q bf16 4 MB   [0,4); later fh bf16
    u16*   wt1 = (u16*)(w + (4u<<20));           // 768x256 bf16
    u16*   wt2 = (u16*)(w + (4u<<20) + 393216);
    u16*   wt3 = (u16*)(w + (4u<<20) + 655360);
    u16*   wt4 = (u16*)(w + (4u<<20) + 786432);
    u32*   mw  = (u32*)(w + (4u<<20) + 917504);  // mask bitmap 32 KB
    u16*   nxb = (u16*)(w + (5u<<20));           // node bf16 4 MB  [5,9)
    u16*   exb = (u16*)(w + (9u<<20));           // edge bf16 8 MB  [9,17); later xbh
    u16*   kb  = (u16*)(w + (17u<<20));          // K bf16 12 MB    [17,30)
    u16*   vt  = (u16*)(w + (30u<<20));          // V^T bf16 12 MB  [30,43)
    float* cx  = (float*)(w + (43u<<20));        // ctx / ff out f32 8 MB [43,52)
    float* xb  = (float*)(w + (52u<<20));        // x after LN1 f32  8 MB [52,61)
    u16*   xbh = exb;                            // LN1 bf16 out (edge_bf dead)
    u16*   fh  = qb;                             // ffn hidden bf16 (qb dead)

    prep_k<<<dim3(4096, 7), 256, 0, stream>>>(
        W1, W2, l1w, l2w, node_x, edge_x, (const u32*)mask,
        wt1, wt2, wt3, wt4, nxb, exb, mw);
    gemm_mfma<128, 128, 768, 256, 0><<<dim3(kM1 / 128, 6), 256, 0, stream>>>(
        nxb, wt1, b1, qb, kb, vt);
    gemm_mfma<128, 128, 512, 256, 1><<<dim3(kB * kEL / 128, 4), 256, 0, stream>>>(
        exb, wt2, b2, kb, vt, nullptr);
    attn_mfma<<<kB * kH * 8, 256, 0, stream>>>(qb, kb, vt, mask, mw, cx);
    ln_k<true><<<kM1 / 4, 256, 0, stream>>>(node_x, cx, g1, be1, xb, xbh);
    gemm_mfma<64, 128, 256, 256, 2><<<dim3(kM1 / 64, 2), 256, 0, stream>>>(
        xbh, wt3, l1b, fh, nullptr, nullptr);
    gemm_mfma<64, 128, 256, 256, 3><<<dim3(kM1 / 64, 2), 256, 0, stream>>>(
        fh, wt4, l2b, cx, nullptr, nullptr);
    ln_k<false><<<kM1 / 4, 256, 0, stream>>>(xb, cx, g2, be2, (float*)d_out, nullptr);
}

// Round 17
// 95.242 us; speedup vs baseline: 1.1124x; 1.0460x over previous
//
#include <hip/hip_runtime.h>
#include <hip/hip_bf16.h>

using u16 = unsigned short;
using u32 = unsigned int;
using u64 = unsigned long long;
typedef __attribute__((ext_vector_type(8))) short short8;
typedef __attribute__((ext_vector_type(4))) float f32x4;
typedef __attribute__((ext_vector_type(16))) float f32x16;
typedef __attribute__((ext_vector_type(4))) u32 u32x4;

constexpr int kB = 16, kNL = 512, kEL = 1024, kD = 256, kH = 8, kHD = 32;
constexpr int kS = kNL + kEL;      // 1536
constexpr int kM1 = kB * kNL;      // 8192
constexpr float kScale = 0.17677669529663687f;  // 1/sqrt(32)
constexpr float kLog2e = 1.4426950408889634f;
constexpr float kQS = kScale * kLog2e;          // folded into q at GEMM1 epilogue
constexpr float kEps = 1e-5f;

__device__ __forceinline__ u16 f2bh(float f) {
    __hip_bfloat16 h = __float2bfloat16(f);   // RNE
    return __builtin_bit_cast(u16, h);
}
__device__ __forceinline__ u32 packbf(float lo, float hi) {  // trunc pair (P >= 0)
    return (__float_as_uint(hi) & 0xffff0000u) | (__float_as_uint(lo) >> 16);
}
__device__ __forceinline__ void load4(const float* p, float* o) {
    float4 v = *reinterpret_cast<const float4*>(p);
    o[0] = v.x; o[1] = v.y; o[2] = v.z; o[3] = v.w;
}
__device__ __forceinline__ f32x16 fzero16() {
    f32x16 z;
    #pragma unroll
    for (int i = 0; i < 16; ++i) z[i] = 0.f;
    return z;
}

// ---------- prep: weight transpose/cast + input bf16 casts + mask bitmap ----------
__global__ __launch_bounds__(256) void prep_k(
    const float* __restrict__ W1, const float* __restrict__ W2,
    const float* __restrict__ l1w, const float* __restrict__ l2w,
    const float* __restrict__ nodef, const float* __restrict__ edgef,
    const u32* __restrict__ mask,
    u16* __restrict__ Wt1, u16* __restrict__ Wt2,
    u16* __restrict__ Wt3, u16* __restrict__ Wt4,
    u16* __restrict__ nodeb, u16* __restrict__ edgeb,
    u32* __restrict__ Mw)
{
    const int sec = blockIdx.y, bid = blockIdx.x, t = threadIdx.x;
    if (sec == 6) {   // mask bitmap: one wave per row
        if (bid >= 2048) return;
        const int row = bid * 4 + (t >> 6);
        const int l = t & 63;
        const u32* mr = mask + (size_t)row * (kS / 4);
        u32 word = 0;
        #pragma unroll
        for (int k = 0; k < 6; ++k) {
            const u32 v = mr[k * 64 + l];
            const u64 bal = __ballot(v != 0);
            word |= (((bal) & 0xffffull) ? 1u : 0u) << (k * 4 + 0);
            word |= (((bal >> 16) & 0xffffull) ? 1u : 0u) << (k * 4 + 1);
            word |= (((bal >> 32) & 0xffffull) ? 1u : 0u) << (k * 4 + 2);
            word |= (((bal >> 48) & 0xffffull) ? 1u : 0u) << (k * 4 + 3);
        }
        if (l == 0) Mw[row] = word;
        return;
    }
    if (sec >= 4) {   // bulk bf16 casts
        const float* src = (sec == 4) ? nodef : edgef;
        u16* dst = (sec == 4) ? nodeb : edgeb;
        const int nblk = (sec == 4) ? 2048 : 4096;
        if (bid >= nblk) return;
        const int i = bid * 1024 + t * 4;
        float v[4]; load4(src + i, v);
        ushort4 o = {f2bh(v[0]), f2bh(v[1]), f2bh(v[2]), f2bh(v[3])};
        *reinterpret_cast<ushort4*>(dst + i) = o;
        return;
    }
    if (sec >= 2) {
        if (bid >= 64) return;
        const float* src = (sec == 2) ? l1w : l2w;
        u16* dst = (sec == 2) ? Wt3 : Wt4;
        const int i = bid * 1024 + t * 4;
        float v[4]; load4(src + i, v);
        ushort4 o = {f2bh(v[0]), f2bh(v[1]), f2bh(v[2]), f2bh(v[3])};
        *reinterpret_cast<ushort4*>(dst + i) = o;
        return;
    }
    const int N = (sec == 0) ? 768 : 512;
    if (bid >= 8 * (N / 32)) return;
    const float* src = (sec == 0) ? W1 : W2;
    u16* dst = (sec == 0) ? Wt1 : Wt2;
    const int tk = bid / (N / 32), tn = bid % (N / 32);
    __shared__ float T[32][33];
    {
        const int k = t >> 3, n4 = (t & 7) * 4;
        float v[4]; load4(src + (size_t)(tk * 32 + k) * N + tn * 32 + n4, v);
        T[n4+0][k] = v[0]; T[n4+1][k] = v[1]; T[n4+2][k] = v[2]; T[n4+3][k] = v[3];
    }
    __syncthreads();
    {
        const int n = t >> 3, k4 = (t & 7) * 4;
        ushort4 o = {f2bh(T[n][k4+0]), f2bh(T[n][k4+1]),
                     f2bh(T[n][k4+2]), f2bh(T[n][k4+3])};
        *reinterpret_cast<ushort4*>(dst + (size_t)(tn*32 + n) * 256 + tk*32 + k4) = o;
    }
}

// ---------- GEMM body (128x128 tile, 4 waves 2x2, BK=32) ----------
// MODE 0: qkv scatter; MODE 1: kv_edge scatter.
template<int N, int K, int MODE>
__device__ __forceinline__ void gemm_body128(
    const u16* __restrict__ A, const u16* __restrict__ Wt,
    const float* __restrict__ bias,
    void* __restrict__ o0v, void* __restrict__ o1v, void* __restrict__ o2v,
    int bx, int by, u16* AsB, u16* BsB)   // AsB/BsB: 2 buffers of 128*40 each
{
    const int t = threadIdx.x;
    const int w = t >> 6, l = t & 63;
    const int wr = w >> 1, wc = w & 1;
    const int lq = l & 15, lg = l >> 4;
    const int bm = bx * 128, bn = by * 128;

    f32x4 acc[4][4];
    #pragma unroll
    for (int mi = 0; mi < 4; ++mi)
        #pragma unroll
        for (int ni = 0; ni < 4; ++ni) acc[mi][ni] = (f32x4){0.f, 0.f, 0.f, 0.f};

    auto stage = [&](int buf, int kk) {
        u16* As = AsB + buf * (128 * 40);
        u16* Bs = BsB + buf * (128 * 40);
        const int m = t >> 1, kh = (t & 1) * 16;
        const u16* ap = A + (size_t)(bm + m) * K + kk + kh;
        *reinterpret_cast<short8*>(&As[m * 40 + kh]) = *reinterpret_cast<const short8*>(ap);
        *reinterpret_cast<short8*>(&As[m * 40 + kh + 8]) = *reinterpret_cast<const short8*>(ap + 8);
        const u16* bp = Wt + (size_t)(bn + m) * K + kk + kh;
        *reinterpret_cast<short8*>(&Bs[m * 40 + kh]) = *reinterpret_cast<const short8*>(bp);
        *reinterpret_cast<short8*>(&Bs[m * 40 + kh + 8]) = *reinterpret_cast<const short8*>(bp + 8);
    };

    stage(0, 0);
    __syncthreads();
    int buf = 0;
    for (int kk = 0; kk < K; kk += 32) {
        if (kk + 32 < K) stage(buf ^ 1, kk + 32);
        const u16* As = AsB + buf * (128 * 40);
        const u16* Bs = BsB + buf * (128 * 40);
        short8 bf[4];
        #pragma unroll
        for (int ni = 0; ni < 4; ++ni)
            bf[ni] = *reinterpret_cast<const short8*>(
                &Bs[(wc * 64 + ni * 16 + lq) * 40 + lg * 8]);
        #pragma unroll
        for (int mi = 0; mi < 4; ++mi) {
            const short8 af = *reinterpret_cast<const short8*>(
                &As[(wr * 64 + mi * 16 + lq) * 40 + lg * 8]);
            #pragma unroll
            for (int ni = 0; ni < 4; ++ni)
                acc[mi][ni] = __builtin_amdgcn_mfma_f32_16x16x32_bf16(
                    af, bf[ni], acc[mi][ni], 0, 0, 0);
        }
        __syncthreads();
        buf ^= 1;
    }

    #pragma unroll
    for (int mi = 0; mi < 4; ++mi) {
        #pragma unroll
        for (int ni = 0; ni < 4; ++ni) {
            const int cg = bn + wc * 64 + ni * 16 + lq;
            const int rg0 = bm + wr * 64 + mi * 16 + lg * 4;
            const float bv = bias[cg];
            float y[4];
            #pragma unroll
            for (int r = 0; r < 4; ++r) y[r] = acc[mi][ni][r] + bv;
            if constexpr (MODE == 0) {
                u16* qo = (u16*)o0v; u16* ko = (u16*)o1v; u16* vt = (u16*)o2v;
                const int bidx = rg0 >> 9, key = rg0 & 511;
                if (cg < 256) {
                    #pragma unroll
                    for (int r = 0; r < 4; ++r)
                        qo[(size_t)(rg0 + r) * kD + cg] = f2bh(y[r] * kQS);
                } else if (cg < 512) {
                    #pragma unroll
                    for (int r = 0; r < 4; ++r)
                        ko[((size_t)bidx * kS + key + r) * kD + (cg - 256)] = f2bh(y[r]);
                } else {
                    const int d0 = cg - 512, hh = d0 >> 5, dd = d0 & 31;
                    ushort4 o = {f2bh(y[0]), f2bh(y[1]), f2bh(y[2]), f2bh(y[3])};
                    *reinterpret_cast<ushort4*>(
                        vt + ((size_t)(bidx * kH + hh) * kHD + dd) * kS + key) = o;
                }
            } else {
                u16* ko = (u16*)o0v; u16* vt = (u16*)o1v;
                const int bidx = rg0 >> 10, key = kNL + (rg0 & 1023);
                if (cg < 256) {
                    #pragma unroll
                    for (int r = 0; r < 4; ++r)
                        ko[((size_t)bidx * kS + key + r) * kD + cg] = f2bh(y[r]);
                } else {
                    const int d0 = cg - 256, hh = d0 >> 5, dd = d0 & 31;
                    ushort4 o = {f2bh(y[0]), f2bh(y[1]), f2bh(y[2]), f2bh(y[3])};
                    *reinterpret_cast<ushort4*>(
                        vt + ((size_t)(bidx * kH + hh) * kHD + dd) * kS + key) = o;
                }
            }
        }
    }
}

// one launch for both projection GEMMs (896 blocks: 384 node + 512 edge)
__global__ __launch_bounds__(256) void qkv_both(
    const u16* __restrict__ nxb, const u16* __restrict__ exb,
    const u16* __restrict__ wt1, const u16* __restrict__ wt2,
    const float* __restrict__ b1, const float* __restrict__ b2,
    u16* __restrict__ qb, u16* __restrict__ kb, u16* __restrict__ vt)
{
    __shared__ u16 AsB[2 * 128 * 40];
    __shared__ u16 BsB[2 * 128 * 40];
    const int bid = blockIdx.x;
    if (bid < 384) {
        gemm_body128<768, 256, 0>(nxb, wt1, b1, qb, kb, vt,
                                  bid & 63, bid >> 6, AsB, BsB);
    } else {
        const int r = bid - 384;
        gemm_body128<512, 256, 1>(exb, wt2, b2, kb, vt, nullptr,
                                  r & 127, r >> 7, AsB, BsB);
    }
}

// ---------- FFN1: relu(A@W^T+b) -> bf16, BM=64 BN=128 ----------
__global__ __launch_bounds__(256) void ffn1_k(
    const u16* __restrict__ A, const u16* __restrict__ Wt,
    const float* __restrict__ bias, u16* __restrict__ out)
{
    __shared__ u16 AsB[2][64 * 40];
    __shared__ u16 BsB[2][128 * 40];
    const int t = threadIdx.x;
    const int w = t >> 6, l = t & 63;
    const int wr = w >> 1, wc = w & 1;
    const int lq = l & 15, lg = l >> 4;
    const int bm = blockIdx.x * 64, bn = blockIdx.y * 128;
    constexpr int K = 256;

    f32x4 acc[2][4];
    #pragma unroll
    for (int mi = 0; mi < 2; ++mi)
        #pragma unroll
        for (int ni = 0; ni < 4; ++ni) acc[mi][ni] = (f32x4){0.f, 0.f, 0.f, 0.f};

    auto stage = [&](int buf, int kk) {
        {
            const int m = t >> 2, kq = (t & 3) * 8;
            *reinterpret_cast<short8*>(&AsB[buf][m * 40 + kq]) =
                *reinterpret_cast<const short8*>(A + (size_t)(bm + m) * K + kk + kq);
        }
        {
            const int n = t >> 1, kh = (t & 1) * 16;
            const u16* bp = Wt + (size_t)(bn + n) * K + kk + kh;
            *reinterpret_cast<short8*>(&BsB[buf][n * 40 + kh]) =
                *reinterpret_cast<const short8*>(bp);
            *reinterpret_cast<short8*>(&BsB[buf][n * 40 + kh + 8]) =
                *reinterpret_cast<const short8*>(bp + 8);
        }
    };

    stage(0, 0);
    __syncthreads();
    int buf = 0;
    for (int kk = 0; kk < K; kk += 32) {
        if (kk + 32 < K) stage(buf ^ 1, kk + 32);
        short8 bf[4];
        #pragma unroll
        for (int ni = 0; ni < 4; ++ni)
            bf[ni] = *reinterpret_cast<const short8*>(
                &BsB[buf][(wc * 64 + ni * 16 + lq) * 40 + lg * 8]);
        #pragma unroll
        for (int mi = 0; mi < 2; ++mi) {
            const short8 af = *reinterpret_cast<const short8*>(
                &AsB[buf][(wr * 32 + mi * 16 + lq) * 40 + lg * 8]);
            #pragma unroll
            for (int ni = 0; ni < 4; ++ni)
                acc[mi][ni] = __builtin_amdgcn_mfma_f32_16x16x32_bf16(
                    af, bf[ni], acc[mi][ni], 0, 0, 0);
        }
        __syncthreads();
        buf ^= 1;
    }

    #pragma unroll
    for (int mi = 0; mi < 2; ++mi) {
        #pragma unroll
        for (int ni = 0; ni < 4; ++ni) {
            const int cg = bn + wc * 64 + ni * 16 + lq;
            const int rg0 = bm + wr * 32 + mi * 16 + lg * 4;
            const float bv = bias[cg];
            #pragma unroll
            for (int r = 0; r < 4; ++r)
                out[(size_t)(rg0 + r) * 256 + cg] = f2bh(fmaxf(acc[mi][ni][r] + bv, 0.f));
        }
    }
}

// ---------- FFN2 + residual + LN2 fused: BM=32, BN=256 (full row) ----------
// out = LayerNorm(xb + A@Wt^T + b) * g + be  -> f32 d_out
__global__ __launch_bounds__(256) void ffn2_ln2_k(
    const u16* __restrict__ A, const u16* __restrict__ Wt,
    const float* __restrict__ bias, const float* __restrict__ xb,
    const float* __restrict__ gam, const float* __restrict__ bet,
    float* __restrict__ out)
{
    __shared__ __align__(16) char smem[46080];
    u16* AsB = (u16*)smem;                       // 2 x 32*40
    u16* BsB = (u16*)(smem + 2 * 32 * 40 * 2);   // 2 x 256*40
    float* lnb = (float*)smem;                   // 32 x 260 (reused after K-loop)
    const int t = threadIdx.x;
    const int w = t >> 6, l = t & 63;
    const int wr = w >> 1, wc = w & 1;
    const int lq = l & 15, lg = l >> 4;
    const int bm = blockIdx.x * 32;
    constexpr int K = 256;

    f32x4 acc[8];
    #pragma unroll
    for (int ni = 0; ni < 8; ++ni) acc[ni] = (f32x4){0.f, 0.f, 0.f, 0.f};

    auto stage = [&](int buf, int kk) {
        {
            const int m = t >> 3, kq = (t & 7) * 4;
            *reinterpret_cast<ushort4*>(&AsB[buf * 32 * 40 + m * 40 + kq]) =
                *reinterpret_cast<const ushort4*>(A + (size_t)(bm + m) * K + kk + kq);
        }
        {
            const int n = t;
            const u16* bp = Wt + (size_t)n * K + kk;
            u16* dst = &BsB[buf * 256 * 40 + n * 40];
            #pragma unroll
            for (int j = 0; j < 4; ++j)
                *reinterpret_cast<short8*>(dst + j * 8) =
                    *reinterpret_cast<const short8*>(bp + j * 8);
        }
    };

    stage(0, 0);
    __syncthreads();
    int buf = 0;
    for (int kk = 0; kk < K; kk += 32) {
        if (kk + 32 < K) stage(buf ^ 1, kk + 32);
        short8 bf[8];
        #pragma unroll
        for (int ni = 0; ni < 8; ++ni)
            bf[ni] = *reinterpret_cast<const short8*>(
                &BsB[buf * 256 * 40 + (wc * 128 + ni * 16 + lq) * 40 + lg * 8]);
        const short8 af = *reinterpret_cast<const short8*>(
            &AsB[buf * 32 * 40 + (wr * 16 + lq) * 40 + lg * 8]);
        #pragma unroll
        for (int ni = 0; ni < 8; ++ni)
            acc[ni] = __builtin_amdgcn_mfma_f32_16x16x32_bf16(af, bf[ni], acc[ni], 0, 0, 0);
        __syncthreads();
        buf ^= 1;
    }

    // stage y = acc + bias into LDS rows (all K-loop reads are behind the barrier)
    #pragma unroll
    for (int ni = 0; ni < 8; ++ni) {
        const int cg = wc * 128 + ni * 16 + lq;
        const int rl0 = wr * 16 + lg * 4;
        const float bv = bias[cg];
        #pragma unroll
        for (int r = 0; r < 4; ++r)
            lnb[(rl0 + r) * 260 + cg] = acc[ni][r] + bv;
    }
    __syncthreads();

    // LN pass: wave w handles rows w*8 .. w*8+7
    #pragma unroll
    for (int rr = 0; rr < 8; ++rr) {
        const int rl = w * 8 + rr;
        const int row = bm + rl;
        float xv[4];
        float4 yv = *reinterpret_cast<const float4*>(&lnb[rl * 260 + l * 4]);
        float rv[4];
        load4(xb + (size_t)row * kD + l * 4, rv);
        xv[0] = yv.x + rv[0]; xv[1] = yv.y + rv[1];
        xv[2] = yv.z + rv[2]; xv[3] = yv.w + rv[3];
        float s = xv[0] + xv[1] + xv[2] + xv[3];
        float q = xv[0]*xv[0] + xv[1]*xv[1] + xv[2]*xv[2] + xv[3]*xv[3];
        #pragma unroll
        for (int off = 1; off < 64; off <<= 1) {
            s += __shfl_xor(s, off);
            q += __shfl_xor(q, off);
        }
        const float mean = s * (1.0f / kD);
        const float var = q * (1.0f / kD) - mean * mean;
        const float rs = rsqrtf(var + kEps);
        float gv[4], bv[4];
        load4(gam + l * 4, gv);
        load4(bet + l * 4, bv);
        float4 o;
        o.x = (xv[0] - mean) * rs * gv[0] + bv[0];
        o.y = (xv[1] - mean) * rs * gv[1] + bv[1];
        o.z = (xv[2] - mean) * rs * gv[2] + bv[2];
        o.w = (xv[3] - mean) * rs * gv[3] + bv[3];
        *reinterpret_cast<float4*>(out + (size_t)row * kD + l * 4) = o;
    }
}

// ---------- MFMA 32x32 flash attention, split-K x4, 2 q-groups per wave (r14) ----------
__global__ __launch_bounds__(256) void attn_mfma(
    const u16* __restrict__ Qb, const u16* __restrict__ Kb,
    const u16* __restrict__ VTb, const unsigned char* __restrict__ mask,
    const u32* __restrict__ Mw, float* __restrict__ O)
{
    __shared__ float mba[4][64][17];
    __shared__ float mbb[4][64][17];
    const int t = threadIdx.x;
    const int w = t >> 6, l = t & 63;
    const int q32 = l & 31, hi = l >> 5;
    const int bid = blockIdx.x;
    const int h = bid & 7;
    const int qt = (bid >> 3) & 7;
    const int b = bid >> 6;
    const int qra = qt * 64 + q32;
    const int qrb = qra + 32;

    const u16* qpa = Qb + ((size_t)(b * kNL) + qra) * kD + h * kHD;
    const u16* qpb = Qb + ((size_t)(b * kNL) + qrb) * kD + h * kHD;
    const short8 qf0a = *reinterpret_cast<const short8*>(qpa + hi * 8);
    const short8 qf1a = *reinterpret_cast<const short8*>(qpa + 16 + hi * 8);
    const short8 qf0b = *reinterpret_cast<const short8*>(qpb + hi * 8);
    const short8 qf1b = *reinterpret_cast<const short8*>(qpb + 16 + hi * 8);

    const u16* kbase  = Kb  + ((size_t)b * kS) * kD + h * kHD;
    const u16* vtbase = VTb + ((size_t)(b * kH + h) * kHD) * kS;
    const unsigned char* mra = mask + ((size_t)(b * kNL) + qra) * kS;
    const unsigned char* mrb = mask + ((size_t)(b * kNL) + qrb) * kS;
    const u32 mbitsa = Mw[b * kNL + qra];
    const u32 mbitsb = Mw[b * kNL + qrb];

    f32x16 acca = fzero16(), accb = fzero16();
    float la = 0.f, lb = 0.f;

#define HALFG(kfA, kfB, vfA, vfB, keyh, QF0, QF1, ACC, LRUN, COLD, MROW) do {  \
        f32x16 s = __builtin_amdgcn_mfma_f32_32x32x16_bf16(kfA, QF0, fzero16(), 0, 0, 0); \
        s = __builtin_amdgcn_mfma_f32_32x32x16_bf16(kfB, QF1, s, 0, 0, 0);     \
        float e[16];                                                           \
        _Pragma("unroll")                                                      \
        for (int n = 0; n < 16; ++n) e[n] = __builtin_amdgcn_exp2f(s[n]);      \
        if (COLD) {                                                            \
            _Pragma("unroll")                                                  \
            for (int n = 0; n < 16; ++n) {                                     \
                const int key = (keyh) + (n & 3) + 8 * (n >> 2) + 4 * hi;      \
                if (MROW[key]) e[n] = 0.f;                                     \
            }                                                                  \
        }                                                                      \
        u32 pk[8];                                                             \
        _Pragma("unroll")                                                      \
        for (int qd = 0; qd < 4; ++qd) {                                       \
            LRUN += (e[4*qd] + e[4*qd+1]) + (e[4*qd+2] + e[4*qd+3]);           \
            pk[2*qd]   = packbf(e[4*qd],   e[4*qd+1]);                         \
            pk[2*qd+1] = packbf(e[4*qd+2], e[4*qd+3]);                         \
        }                                                                      \
        {                                                                      \
            u32 xa = pk[0], ya = pk[2], xb_ = pk[1], yb_ = pk[3];              \
            asm("v_permlane32_swap_b32 %0, %1" : "+v"(xa), "+v"(ya));          \
            asm("v_permlane32_swap_b32 %0, %1" : "+v"(xb_), "+v"(yb_));        \
            const short8 pb = __builtin_bit_cast(short8, (u32x4){xa, xb_, ya, yb_}); \
            __builtin_amdgcn_s_setprio(1);                                     \
            ACC = __builtin_amdgcn_mfma_f32_32x32x16_bf16(vfA, pb, ACC, 0, 0, 0); \
            __builtin_amdgcn_s_setprio(0);                                     \
        }                                                                      \
        {                                                                      \
            u32 xa = pk[4], ya = pk[6], xb_ = pk[5], yb_ = pk[7];              \
            asm("v_permlane32_swap_b32 %0, %1" : "+v"(xa), "+v"(ya));          \
            asm("v_permlane32_swap_b32 %0, %1" : "+v"(xb_), "+v"(yb_));        \
            const short8 pb = __builtin_bit_cast(short8, (u32x4){xa, xb_, ya, yb_}); \
            __builtin_amdgcn_s_setprio(1);                                     \
            ACC = __builtin_amdgcn_mfma_f32_32x32x16_bf16(vfB, pb, ACC, 0, 0, 0); \
            __builtin_amdgcn_s_setprio(0);                                     \
        }                                                                      \
} while (0)

    const int ktBeg = w * 6, ktEnd = ktBeg + 6;
    for (int kt = ktBeg; kt < ktEnd; ++kt) {
        const int key0 = kt * 64;
        const u16* krow = kbase + (size_t)(key0 + q32) * kD + hi * 8;
        const u16* vrow = vtbase + (size_t)q32 * kS + key0 + hi * 8;
        const short8 a0 = *reinterpret_cast<const short8*>(krow);
        const short8 a1 = *reinterpret_cast<const short8*>(krow + 16);
        const short8 a2 = *reinterpret_cast<const short8*>(krow + 32 * kD);
        const short8 a3 = *reinterpret_cast<const short8*>(krow + 32 * kD + 16);
        const short8 v0 = *reinterpret_cast<const short8*>(vrow);
        const short8 v1 = *reinterpret_cast<const short8*>(vrow + 16);
        const short8 v2 = *reinterpret_cast<const short8*>(vrow + 32);
        const short8 v3 = *reinterpret_cast<const short8*>(vrow + 48);
        const bool colda = __any(((mbitsa >> kt) & 1u) != 0u);
        const bool coldb = __any(((mbitsb >> kt) & 1u) != 0u);
        HALFG(a0, a1, v0, v1, key0, qf0a, qf1a, acca, la, colda, mra);
        HALFG(a0, a1, v0, v1, key0, qf0b, qf1b, accb, lb, coldb, mrb);
        HALFG(a2, a3, v2, v3, key0 + 32, qf0a, qf1a, acca, la, colda, mra);
        HALFG(a2, a3, v2, v3, key0 + 32, qf0b, qf1b, accb, lb, coldb, mrb);
    }
#undef HALFG

    la += __shfl_xor(la, 32);
    lb += __shfl_xor(lb, 32);

    mba[w][l][0] = la;
    mbb[w][l][0] = lb;
    #pragma unroll
    for (int j = 0; j < 16; ++j) { mba[w][l][1 + j] = acca[j]; mbb[w][l][1 + j] = accb[j]; }
    __syncthreads();
    if (w == 0) {
        {
            float lt = la;
            float ov[16];
            #pragma unroll
            for (int i = 0; i < 16; ++i) ov[i] = acca[i];
            #pragma unroll
            for (int j = 1; j < 4; ++j) {
                lt += mba[j][l][0];
                #pragma unroll
                for (int i = 0; i < 16; ++i) ov[i] += mba[j][l][1 + i];
            }
            const float inv = (lt > 0.f) ? 1.f / lt : 0.f;
            float* orow = O + ((size_t)(b * kNL) + qra) * kD + h * kHD;
            #pragma unroll
            for (int qd = 0; qd < 4; ++qd) {
                float4 o = {ov[4*qd+0] * inv, ov[4*qd+1] * inv,
                            ov[4*qd+2] * inv, ov[4*qd+3] * inv};
                *reinterpret_cast<float4*>(orow + qd * 8 + 4 * hi) = o;
            }
        }
        {
            float lt = lb;
            float ov[16];
            #pragma unroll
            for (int i = 0; i < 16; ++i) ov[i] = accb[i];
            #pragma unroll
            for (int j = 1; j < 4; ++j) {
                lt += mbb[j][l][0];
                #pragma unroll
                for (int i = 0; i < 16; ++i) ov[i] += mbb[j][l][1 + i];
            }
            const float inv = (lt > 0.f) ? 1.f / lt : 0.f;
            float* orow = O + ((size_t)(b * kNL) + qrb) * kD + h * kHD;
            #pragma unroll
            for (int qd = 0; qd < 4; ++qd) {
                float4 o = {ov[4*qd+0] * inv, ov[4*qd+1] * inv,
                            ov[4*qd+2] * inv, ov[4*qd+3] * inv};
                *reinterpret_cast<float4*>(orow + qd * 8 + 4 * hi) = o;
            }
        }
    }
}

// out = LayerNorm(a + r) * gamma + beta. DUAL: also write bf16 copy.
template<bool DUAL>
__global__ __launch_bounds__(256) void ln_k(
    const float* __restrict__ a_, const float* __restrict__ r,
    const float* __restrict__ gam, const float* __restrict__ bet,
    float* __restrict__ out_, u16* __restrict__ outh)
{
    const int row = blockIdx.x * 4 + (threadIdx.x >> 6);
    const int lane = threadIdx.x & 63;
    const size_t base = (size_t)row * kD + lane * 4;
    float xv[4];
    load4(a_ + base, xv);
    float rv[4];
    load4(r + base, rv);
    #pragma unroll
    for (int t = 0; t < 4; ++t) xv[t] += rv[t];
    float s = xv[0] + xv[1] + xv[2] + xv[3];
    float q = xv[0]*xv[0] + xv[1]*xv[1] + xv[2]*xv[2] + xv[3]*xv[3];
    #pragma unroll
    for (int off = 1; off < 64; off <<= 1) {
        s += __shfl_xor(s, off);
        q += __shfl_xor(q, off);
    }
    const float mean = s * (1.0f / kD);
    const float var = q * (1.0f / kD) - mean * mean;
    const float rs = rsqrtf(var + kEps);
    float gv[4], bv[4];
    load4(gam + lane * 4, gv);
    load4(bet + lane * 4, bv);
    float y[4];
    #pragma unroll
    for (int t = 0; t < 4; ++t) y[t] = (xv[t] - mean) * rs * gv[t] + bv[t];
    float4 o = {y[0], y[1], y[2], y[3]};
    *reinterpret_cast<float4*>(out_ + base) = o;
    if constexpr (DUAL) {
        ushort4 ob = {f2bh(y[0]), f2bh(y[1]), f2bh(y[2]), f2bh(y[3])};
        *reinterpret_cast<ushort4*>(outh + base) = ob;
    }
}

extern "C" void kernel_launch(void* const* d_in, const int* in_sizes, int n_in,
                              void* d_out, int out_size, void* d_ws, size_t ws_size,
                              hipStream_t stream)
{
    const float* node_x = (const float*)d_in[0];
    const float* edge_x = (const float*)d_in[1];
    const unsigned char* mask = (const unsigned char*)d_in[2];
    const float* W1  = (const float*)d_in[3];
    const float* b1  = (const float*)d_in[4];
    const float* W2  = (const float*)d_in[5];
    const float* b2  = (const float*)d_in[6];
    const float* l1w = (const float*)d_in[7];
    const float* l1b = (const float*)d_in[8];
    const float* l2w = (const float*)d_in[9];
    const float* l2b = (const float*)d_in[10];
    const float* g1  = (const float*)d_in[11];
    const float* be1 = (const float*)d_in[12];
    const float* g2  = (const float*)d_in[13];
    const float* be2 = (const float*)d_in[14];

    char* w = (char*)d_ws;
    u16*   qb  = (u16*)(w);                      // q bf16 4 MB   [0,4); later fh bf16
    u16*   wt1 = (u16*)(w + (4u<<20));           // 768x256 bf16
    u16*   wt2 = (u16*)(w + (4u<<20) + 393216);
    u16*   wt3 = (u16*)(w + (4u<<20) + 655360);
    u16*   wt4 = (u16*)(w + (4u<<20) + 786432);
    u32*   mw  = (u32*)(w + (4u<<20) + 917504);  // mask bitmap 32 KB
    u16*   nxb = (u16*)(w + (5u<<20));           // node bf16 4 MB  [5,9)
    u16*   exb = (u16*)(w + (9u<<20));           // edge bf16 8 MB  [9,17); later xbh
    u16*   kb  = (u16*)(w + (17u<<20));          // K bf16 12 MB    [17,30)
    u16*   vt  = (u16*)(w + (30u<<20));          // V^T bf16 12 MB  [30,43)
    float* cx  = (float*)(w + (43u<<20));        // ctx f32 8 MB    [43,52)
    float* xb  = (float*)(w + (52u<<20));        // x after LN1 f32 [52,61)
    u16*   xbh = exb;                            // LN1 bf16 out (edge_bf dead)
    u16*   fh  = qb;                             // ffn hidden bf16 (qb dead)

    prep_k<<<dim3(4096, 7), 256, 0, stream>>>(
        W1, W2, l1w, l2w, node_x, edge_x, (const u32*)mask,
        wt1, wt2, wt3, wt4, nxb, exb, mw);
    qkv_both<<<896, 256, 0, stream>>>(nxb, exb, wt1, wt2, b1, b2, qb, kb, vt);
    attn_mfma<<<kB * kH * 8, 256, 0, stream>>>(qb, kb, vt, mask, mw, cx);
    ln_k<true><<<kM1 / 4, 256, 0, stream>>>(node_x, cx, g1, be1, xb, xbh);
    ffn1_k<<<dim3(kM1 / 64, 2), 256, 0, stream>>>(xbh, wt3, l1b, fh);
    ffn2_ln2_k<<<kM1 / 32, 256, 0, stream>>>(fh, wt4, l2b, xb, g2, be2, (float*)d_out);
}